// Round 10
// baseline (206.969 us; speedup 1.0000x reference)
//
#include <hip/hip_runtime.h>
#include <hip/hip_bf16.h>

typedef unsigned short u16;
typedef unsigned int u32;
typedef unsigned long long u64;

#define N_Q 4096
#define N_M 100000
#define N_M_PAD 100096      // 1564 * 64
#define DDIM 128
#define QTILE 256
#define MTILE 64
#define NCHUNK 48
#define NQT (N_Q / QTILE)                      // 16
#define TOTAL_MT (N_M_PAD / MTILE)             // 1564
#define TPC ((TOTAL_MT + NCHUNK - 1) / NCHUNK) // 33
#define NCAND (NCHUNK * 2 * 3)                 // 288 candidates/query

typedef short bf16x8 __attribute__((ext_vector_type(8)));
typedef float f32x4 __attribute__((ext_vector_type(4)));
typedef float f32x16 __attribute__((ext_vector_type(16)));

static __device__ __forceinline__ u16 f2bf(float v) {
  union { float f; u32 u; } a; a.f = v;
  u32 r = a.u + 0x7fffu + ((a.u >> 16) & 1u);
  return (u16)(r >> 16);
}

static __device__ __forceinline__ void async_copy16(const u16* gp, u16* lp) {
  __builtin_amdgcn_global_load_lds(
      (const __attribute__((address_space(1))) u32*)gp,
      (__attribute__((address_space(3))) u32*)lp, 16, 0, 0);
}

static __device__ __forceinline__ int mbcnt64(u64 m) {
  return __builtin_amdgcn_mbcnt_hi((u32)(m >> 32),
                                   __builtin_amdgcn_mbcnt_lo((u32)m, 0));
}

// ---------------- kernel 1: L2 norms + bf16 normalized copies ----------------
// 16 lanes per row, 4 rows per wave IN FLIGHT: shuffle depth 4, 8B stores.
__global__ __launch_bounds__(256) void knorm(const float* __restrict__ q, const float* __restrict__ m,
                                             u16* __restrict__ qn, u16* __restrict__ mn,
                                             float* __restrict__ qinv, float* __restrict__ minv) {
  const int lane = threadIdx.x & 63;
  const int l16 = lane & 15;
  const int sub = lane >> 4;                              // row-in-group 0..3
  const int wgl = blockIdx.x * 4 + (threadIdx.x >> 6);    // global wave id
  const int step = gridDim.x * 16;                        // rows per grid iteration
  for (int row = wgl * 4 + sub; row < N_Q + N_M_PAD; row += step) {
    const float* src;
    u16* dst;
    int mr = 0;
    bool is_q = (row < N_Q);
    bool pad = false;
    if (is_q) {
      src = q + (size_t)row * DDIM;
      dst = qn + (size_t)row * DDIM;
    } else {
      mr = row - N_Q;
      pad = (mr >= N_M);
      src = m + (size_t)mr * DDIM;
      dst = mn + (size_t)mr * DDIM;
    }
    float4 a, b;
    if (pad) {
      a.x = a.y = a.z = a.w = 0.f;
      b = a;
    } else {
      a = ((const float4*)src)[l16];       // floats l16*4 .. +3
      b = ((const float4*)src)[l16 + 16];  // floats 64 + l16*4 .. +3
    }
    float s = a.x * a.x + a.y * a.y + a.z * a.z + a.w * a.w +
              b.x * b.x + b.y * b.y + b.z * b.z + b.w * b.w;
    #pragma unroll
    for (int off = 1; off < 16; off <<= 1) s += __shfl_xor(s, off, 64);  // within 16-lane group
    float invn = 1.0f / fmaxf(sqrtf(s), 1e-12f);
    u32 p0 = (u32)f2bf(a.x * invn) | ((u32)f2bf(a.y * invn) << 16);
    u32 p1 = (u32)f2bf(a.z * invn) | ((u32)f2bf(a.w * invn) << 16);
    u32 p2 = (u32)f2bf(b.x * invn) | ((u32)f2bf(b.y * invn) << 16);
    u32 p3 = (u32)f2bf(b.z * invn) | ((u32)f2bf(b.w * invn) << 16);
    uint2 w0; w0.x = p0; w0.y = p1;
    uint2 w1; w1.x = p2; w1.y = p3;
    *(uint2*)&dst[l16 * 4] = w0;
    *(uint2*)&dst[64 + l16 * 4] = w1;
    if (l16 == 0) {
      if (is_q) qinv[row] = invn;
      else minv[mr] = pad ? 0.f : invn;
    }
  }
}

// ---------------- kernel 2 helpers ----------------
// 512 threads: each thread stages 2 x 16B units; 1024 units per 64x128 tile (XOR-swizzled)
static __device__ __forceinline__ void stage2(const u16* __restrict__ mn, u16* dst,
                                              int t, const u32* goff, u32 loff0) {
  const u16* gbase = mn + (size_t)t * MTILE * DDIM;
  #pragma unroll
  for (int it = 0; it < 2; ++it)
    async_copy16(gbase + goff[it], dst + loff0 + (u32)(it * 64) * 8);
}

// one 64-row tile with 32x32x16 MFMA: 16 MFMA + batch-max screening epilogue.
// Screening stays IMMEDIATELY after the MFMAs: round-8 lesson — deferring it across the
// barrier extends acc's live range around the loop back-edge and the allocator SPILLS
// acc to scratch every round (FETCH 16.6MB -> 1.55GB, kgemm 92 -> 600 us). Keep acc local.
static __device__ __forceinline__ void tileWork(
    const u16* As, int tl, int wm, int h, int l15, int l31,
    const bf16x8 (&bq)[2][8], float (&tv0)[2], float (&tv1)[2], float (&tv2)[2]) {
  f32x16 acc[2];  // [ni] : ni*32-wide query group
  __builtin_amdgcn_s_setprio(1);
  {
    int c = h ^ l15;  // s = 0
    bf16x8 a = *(const bf16x8*)&As[((wm * 32 + l31) * 16 + c) * 8];
    f32x16 z = {0.f,0.f,0.f,0.f,0.f,0.f,0.f,0.f,0.f,0.f,0.f,0.f,0.f,0.f,0.f,0.f};
    acc[0] = __builtin_amdgcn_mfma_f32_32x32x16_bf16(a, bq[0][0], z, 0, 0, 0);
    acc[1] = __builtin_amdgcn_mfma_f32_32x32x16_bf16(a, bq[1][0], z, 0, 0, 0);
  }
  #pragma unroll
  for (int s = 1; s < 8; ++s) {
    int c = (s * 2 + h) ^ l15;
    bf16x8 a = *(const bf16x8*)&As[((wm * 32 + l31) * 16 + c) * 8];
    acc[0] = __builtin_amdgcn_mfma_f32_32x32x16_bf16(a, bq[0][s], acc[0], 0, 0, 0);
    acc[1] = __builtin_amdgcn_mfma_f32_32x32x16_bf16(a, bq[1][s], acc[1], 0, 0, 0);
  }
  __builtin_amdgcn_s_setprio(0);
  const u32 codeBase = ((u32)tl << 2) | ((u32)h << 1);  // + g -> max 131 < 512
  #pragma unroll
  for (int ni = 0; ni < 2; ++ni) {
    #pragma unroll
    for (int g = 0; g < 2; ++g) {
      float M = fmaxf(
          fmaxf(fmaxf(acc[ni][g * 8 + 0], acc[ni][g * 8 + 1]),
                fmaxf(acc[ni][g * 8 + 2], acc[ni][g * 8 + 3])),
          fmaxf(fmaxf(acc[ni][g * 8 + 4], acc[ni][g * 8 + 5]),
                fmaxf(acc[ni][g * 8 + 6], acc[ni][g * 8 + 7])));
      float pk = __uint_as_float((__float_as_uint(M) & 0xFFFFFE00u) | (codeBase | (u32)g));
      tv2[ni] = __builtin_amdgcn_fmed3f(tv1[ni], tv2[ni], pk);
      tv1[ni] = __builtin_amdgcn_fmed3f(tv0[ni], tv1[ni], pk);
      tv0[ni] = fmaxf(tv0[ni], pk);
    }
  }
}

// ---------------- kernel 2: 512-thread blocks, 3-buffer LDS ring, 3 blocks/CU ----------------
// grid 768 = 16 qtiles x 48 chunks; 48 KB LDS -> 3 blocks/CU (24 waves/CU), three
// phase-offset barrier groups per CU so one block's MFMA fills another's VALU/ds_read gaps.
// Depth-2 prefetch: round r stages tile r+2 into B[(r+2)%3] (the buffer read in round r-1,
// safely behind the barrier), computes B[r%3], then s_waitcnt vmcnt(2) retires exactly
// stage r+1. Never a vmcnt(0) drain in the loop (round-2 lesson: drains REGRESS).
__global__ __launch_bounds__(512, 4) void kgemm(const u16* __restrict__ qn,
                                                const u16* __restrict__ mn,
                                                float* __restrict__ pval) {
  __shared__ u16 B0[MTILE * DDIM];  // 16 KB each, 48 KB total
  __shared__ u16 B1[MTILE * DDIM];
  __shared__ u16 B2[MTILE * DDIM];

  const int id = blockIdx.x;                  // 0..767
  const int xcd = id & 7, sub = id >> 3;      // XCD-aware: 6 chunks per XCD (~3.2 MB in L2)
  const int ch = xcd * 6 + (sub >> 4);        // 0..47
  const int qt = sub & 15;                    // 0..15
  const int tid = threadIdx.x;
  const int wid = tid >> 6, lane = tid & 63;
  const int l15 = lane & 15, l31 = lane & 31, h = lane >> 5;
  const int wm = wid >> 2, wq = wid & 3;

  const int t0 = ch * TPC;
  const int t1 = (t0 + TPC < TOTAL_MT) ? (t0 + TPC) : TOTAL_MT;
  const int nt = t1 - t0;                     // 33 (chunk 47: 13)

  // staging offsets: 2 x 16B units per thread; 1024 units per 64x128 tile (XOR-swizzled)
  u32 goff[2];
  u32 loff0;
  {
    int u0 = wid * 128 + lane;
    loff0 = (u32)(wid * 128) * 8;  // wave-uniform LDS base (HW adds lane*16B)
    #pragma unroll
    for (int it = 0; it < 2; ++it) {
      int u = u0 + it * 64;
      int row = u >> 4, su = u & 15;
      int k8 = su ^ (row & 15);
      goff[it] = (u32)(row * DDIM + k8 * 8);
    }
  }

  // prologue: stage tiles t0, t0+1 (nt >= 13 always)
  stage2(mn, B0, t0 + 0, goff, loff0);
  stage2(mn, B1, t0 + 1, goff, loff0);

  // B (query) fragments for 32x32x16: col = l31-based, k = s*16 + h*8 .. +7 (64 VGPRs)
  bf16x8 bq[2][8];  // [ni][s]
  #pragma unroll
  for (int ni = 0; ni < 2; ++ni) {
    int col = qt * QTILE + wq * 64 + ni * 32 + l31;
    #pragma unroll
    for (int s = 0; s < 8; ++s)
      bq[ni][s] = *(const bf16x8*)&qn[(size_t)col * DDIM + (s * 2 + h) * 8];
  }

  float tv0[2], tv1[2], tv2[2];
  #pragma unroll
  for (int i = 0; i < 2; ++i) { tv0[i] = tv1[i] = tv2[i] = -1e30f; }

  asm volatile("s_waitcnt vmcnt(0)" ::: "memory");  // drain prologue stages (+bq loads)
  asm volatile("s_barrier" ::: "memory");

  // round r: stage min(t0+r+2, t1-1) into B[(r+2)%3]; compute B[r%3];
  // wait vmcnt(2) (retires stage r+1, leaves stage r+2 in flight); bare barrier.
  // Always 2 stage-insts/round so the outstanding-count invariant holds in the tail.
  int r = 0;
  #define ROUND(BC, BS)                                                        \
    {                                                                          \
      int ts = t0 + r + 2;                                                     \
      ts = (ts < t1) ? ts : (t1 - 1);                                          \
      stage2(mn, BS, ts, goff, loff0);                                         \
      tileWork(BC, r, wm, h, l15, l31, bq, tv0, tv1, tv2);                     \
      asm volatile("s_waitcnt vmcnt(2)" ::: "memory");                         \
      asm volatile("s_barrier" ::: "memory");                                  \
      ++r;                                                                     \
      if (r >= nt) break;                                                      \
    }
  while (true) {
    ROUND(B0, B2)
    ROUND(B1, B0)
    ROUND(B2, B1)
  }
  #undef ROUND

  // cross-h merge of sorted-3 lists (one shuffle level), then write 3 survivors per (col, wm)
  #pragma unroll
  for (int ni = 0; ni < 2; ++ni) {
    float a0 = tv0[ni], a1 = tv1[ni], a2 = tv2[ni];
    float b0 = __shfl_xor(a0, 32, 64);
    float b1 = __shfl_xor(a1, 32, 64);
    float b2 = __shfl_xor(a2, 32, 64);
    float n0 = fmaxf(a0, b0);
    float n1 = __builtin_amdgcn_fmed3f(a0, b0, fmaxf(a1, b1));
    float n2 = fmaxf(fmaxf(fminf(a1, b0), fminf(a0, b1)), fmaxf(a2, b2));
    int qlocal = wq * 64 + ni * 32 + l31;
    size_t base = (((size_t)qt * NCHUNK + ch) * QTILE + qlocal) * 6 + wm * 3;
    if (h == 0) {
      pval[base] = n0;
      pval[base + 1] = n1;
    } else {
      pval[base + 2] = n2;
    }
  }
}

// ---------------- kernel 3: radix-select top-8 batches, coalesced fp32 rescore, top-3 ----------------
// 288 candidates/query: lane c < 48 owns chunk c's 6 candidates (pos = lane*6 + i).
__global__ __launch_bounds__(256) void kmerge(const float* __restrict__ pval,
                                              const float* __restrict__ q,
                                              const float* __restrict__ mem,
                                              const float* __restrict__ qinv,
                                              const float* __restrict__ minv,
                                              float* __restrict__ out) {
  __shared__ float sv[4][64];
  __shared__ u32 spk[4][8];   // packed float bits of the 8 winners
  __shared__ u32 spo[4][8];   // candidate positions of the 8 winners
  const int tid = threadIdx.x;
  const int wq = tid >> 6;
  const int lane = tid & 63;
  const int qg = blockIdx.x * 4 + wq;
  const int qt = qg >> 8, ql = qg & 255;

  // load 288 candidates: lane < 48 owns its chunk's 6 consecutive values
  const int c0 = lane * 6;
  float cv[6];
  #pragma unroll
  for (int i = 0; i < 6; ++i) cv[i] = -1e31f;
  if (lane < NCHUNK) {
    size_t b = (((size_t)qt * NCHUNK + lane) * QTILE + ql) * 6;
    #pragma unroll
    for (int i = 0; i < 6; ++i) cv[i] = pval[b + i];
  }

  // order-preserving uint keys (handles negatives)
  u32 k[6];
  #pragma unroll
  for (int i = 0; i < 6; ++i) {
    u32 u = __float_as_uint(cv[i]);
    k[i] = (u & 0x80000000u) ? ~u : (u | 0x80000000u);
  }

  // radix-select the 8th-largest key: 32 uniform rounds of {6 cmp, 3 ballot, 3 popc}.
  u32 t = 0;
  #pragma unroll
  for (int b = 31; b >= 0; --b) {
    u32 cand = t | (1u << b);
    int loc = 0;
    #pragma unroll
    for (int i = 0; i < 6; ++i) loc += (int)(k[i] >= cand);
    u64 M0 = __ballot(loc & 1);
    u64 M1 = __ballot(loc & 2);
    u64 M2 = __ballot(loc & 4);
    int cnt = __popcll(M0) + 2 * __popcll(M1) + 4 * __popcll(M2);
    if (cnt >= 8) t = cand;
  }
  // t = 8th largest key: >=8 keys >= t, <=7 keys > t.

  // slot assignment: strictly-greater first (pos asc), then ==t fills remaining (pos asc).
  {
    u64 G[6], E[6];
    #pragma unroll
    for (int i = 0; i < 6; ++i) {
      G[i] = __ballot(k[i] > t);
      E[i] = __ballot(k[i] == t);
    }
    int c1 = 0, bg = 0, be = 0;
    #pragma unroll
    for (int i = 0; i < 6; ++i) {
      c1 += __popcll(G[i]);
      bg += mbcnt64(G[i]);  // strict winners in earlier lanes
      be += mbcnt64(E[i]);  // ties in earlier lanes
    }
    int og = 0, oe = 0;
    #pragma unroll
    for (int i = 0; i < 6; ++i) {
      int slot = 99;
      if (k[i] > t) { slot = bg + og; ++og; }
      else if (k[i] == t) { slot = c1 + be + oe; ++oe; }
      if (slot < 8) {
        spk[wq][slot] = __float_as_uint(cv[i]);
        spo[wq][slot] = (u32)(c0 + i);
      }
    }
  }
  __syncthreads();

  const float qi = qinv[qg];
  const float* qrow = q + (size_t)qg * DDIM;
  const int e = lane >> 3, f = lane & 7;

  // hoist the query row into registers: reused across all 8 batches
  float4 qv[4];
  #pragma unroll
  for (int i = 0; i < 4; ++i) qv[i] = *(const float4*)&qrow[(f + 8 * i) * 4];

  // rescore top-8 batches, 8 rows each; 8 lanes/row, 128B-coalesced segments.
  // batch decode (32x32x16 layout): code = tl<<2 | h<<1 | g;
  // row = tilebase + wm*32 + g*16 + (e>>2)*8 + h*4 + (e&3)
  #pragma unroll
  for (int p = 0; p < 8; ++p) {
    int bp = (int)spo[wq][p];
    u32 code = spk[wq][p] & 511u;
    int chn = bp / 6;
    int wm = (bp - chn * 6) / 3;
    int tl = (int)(code >> 2), hh = (int)((code >> 1) & 1u), g = (int)(code & 1u);
    int row = (chn * TPC + tl) * MTILE + wm * 32 + g * 16 + (e >> 2) * 8 + hh * 4 + (e & 3);
    bool valid = (row < N_M);
    int ra = valid ? row : 0;
    const float* mrow = mem + (size_t)ra * DDIM;
    float s = 0.f;
    #pragma unroll
    for (int i = 0; i < 4; ++i) {
      float4 mv = *(const float4*)&mrow[(f + 8 * i) * 4];
      s += qv[i].x * mv.x + qv[i].y * mv.y + qv[i].z * mv.z + qv[i].w * mv.w;
    }
    #pragma unroll
    for (int off = 1; off < 8; off <<= 1) s += __shfl_xor(s, off, 64);  // within octet
    s = valid ? (s * qi * minv[ra]) : -1e30f;
    if (f == 0) sv[wq][p * 8 + e] = s;
  }
  __syncthreads();

  // my (row, val): entry = lane -> pass p = lane>>3, elem e2 = lane&7
  float myv = sv[wq][lane];
  {
    int p = lane >> 3, e2 = lane & 7;
    int bp = (int)spo[wq][p];
    u32 code = spk[wq][p] & 511u;
    int chn = bp / 6;
    int wm = (bp - chn * 6) / 3;
    int tl = (int)(code >> 2), hh = (int)((code >> 1) & 1u), g = (int)(code & 1u);
    int row = (chn * TPC + tl) * MTILE + wm * 32 + g * 16 + (e2 >> 2) * 8 + hh * 4 + (e2 & 3);
    int myrow = (row < N_M) ? row : (N_M + lane);

    // 3 selection passes over 64 exact values (val desc, row asc)
    #pragma unroll
    for (int a = 0; a < 3; ++a) {
      float bv = myv; int bi = myrow;
      #pragma unroll
      for (int off = 32; off >= 1; off >>= 1) {
        float ov = __shfl_xor(bv, off, 64);
        int oi = __shfl_xor(bi, off, 64);
        bool g2 = (ov > bv) || (ov == bv && oi < bi);
        bv = g2 ? ov : bv; bi = g2 ? oi : bi;
      }
      if (lane == 0) {
        out[(size_t)qg * 3 + a] = 1.0f - bv;
        out[(size_t)N_Q * 3 + (size_t)qg * 3 + a] = (float)bi;
      }
      if (myrow == bi) myv = -1e31f;
    }
  }
}

extern "C" void kernel_launch(void* const* d_in, const int* in_sizes, int n_in,
                              void* d_out, int out_size, void* d_ws, size_t ws_size,
                              hipStream_t stream) {
  const float* q = (const float*)d_in[0];
  const float* m = (const float*)d_in[1];

  char* ws = (char*)d_ws;
  size_t off = 0;
  u16* qn = (u16*)(ws + off); off += (size_t)N_Q * DDIM * 2;        // 1 MB
  u16* mn = (u16*)(ws + off); off += (size_t)N_M_PAD * DDIM * 2;    // 25.6 MB
  float* qinv = (float*)(ws + off); off += (size_t)N_Q * 4;
  float* minv = (float*)(ws + off); off += (size_t)N_M_PAD * 4;
  float* pval = (float*)(ws + off); off += (size_t)N_Q * NCAND * 4; // 4.7 MB

  knorm<<<1024, 256, 0, stream>>>(q, m, qn, mn, qinv, minv);
  kgemm<<<NQT * NCHUNK, 512, 0, stream>>>(qn, mn, pval);
  kmerge<<<N_Q / 4, 256, 0, stream>>>(pval, q, m, qinv, minv, (float*)d_out);
}

// Round 11
// 200.641 us; speedup vs baseline: 1.0315x; 1.0315x over previous
//
#include <hip/hip_runtime.h>
#include <hip/hip_bf16.h>

typedef unsigned short u16;
typedef unsigned int u32;
typedef unsigned long long u64;

#define N_Q 4096
#define N_M 100000
#define N_M_PAD 100096      // 1564 * 64
#define DDIM 128
#define QTILE 256
#define MTILE 64
#define NCHUNK 32
#define NQT (N_Q / QTILE)                      // 16
#define TOTAL_MT (N_M_PAD / MTILE)             // 1564
#define TPC ((TOTAL_MT + NCHUNK - 1) / NCHUNK) // 49
#define NCAND (NCHUNK * 2 * 3)                 // 192 candidates/query

typedef short bf16x8 __attribute__((ext_vector_type(8)));
typedef float f32x4 __attribute__((ext_vector_type(4)));
typedef float f32x16 __attribute__((ext_vector_type(16)));

static __device__ __forceinline__ u16 f2bf(float v) {
  union { float f; u32 u; } a; a.f = v;
  u32 r = a.u + 0x7fffu + ((a.u >> 16) & 1u);
  return (u16)(r >> 16);
}

static __device__ __forceinline__ void async_copy16(const u16* gp, u16* lp) {
  __builtin_amdgcn_global_load_lds(
      (const __attribute__((address_space(1))) u32*)gp,
      (__attribute__((address_space(3))) u32*)lp, 16, 0, 0);
}

static __device__ __forceinline__ int mbcnt64(u64 m) {
  return __builtin_amdgcn_mbcnt_hi((u32)(m >> 32),
                                   __builtin_amdgcn_mbcnt_lo((u32)m, 0));
}

// ---------------- kernel 1: L2 norms + bf16 normalized copies ----------------
// 16 lanes per row, 4 rows per wave IN FLIGHT: shuffle depth 4, 8B stores.
__global__ __launch_bounds__(256) void knorm(const float* __restrict__ q, const float* __restrict__ m,
                                             u16* __restrict__ qn, u16* __restrict__ mn,
                                             float* __restrict__ qinv, float* __restrict__ minv) {
  const int lane = threadIdx.x & 63;
  const int l16 = lane & 15;
  const int sub = lane >> 4;                              // row-in-group 0..3
  const int wgl = blockIdx.x * 4 + (threadIdx.x >> 6);    // global wave id
  const int step = gridDim.x * 16;                        // rows per grid iteration
  for (int row = wgl * 4 + sub; row < N_Q + N_M_PAD; row += step) {
    const float* src;
    u16* dst;
    int mr = 0;
    bool is_q = (row < N_Q);
    bool pad = false;
    if (is_q) {
      src = q + (size_t)row * DDIM;
      dst = qn + (size_t)row * DDIM;
    } else {
      mr = row - N_Q;
      pad = (mr >= N_M);
      src = m + (size_t)mr * DDIM;
      dst = mn + (size_t)mr * DDIM;
    }
    float4 a, b;
    if (pad) {
      a.x = a.y = a.z = a.w = 0.f;
      b = a;
    } else {
      a = ((const float4*)src)[l16];       // floats l16*4 .. +3
      b = ((const float4*)src)[l16 + 16];  // floats 64 + l16*4 .. +3
    }
    float s = a.x * a.x + a.y * a.y + a.z * a.z + a.w * a.w +
              b.x * b.x + b.y * b.y + b.z * b.z + b.w * b.w;
    #pragma unroll
    for (int off = 1; off < 16; off <<= 1) s += __shfl_xor(s, off, 64);  // within 16-lane group
    float invn = 1.0f / fmaxf(sqrtf(s), 1e-12f);
    u32 p0 = (u32)f2bf(a.x * invn) | ((u32)f2bf(a.y * invn) << 16);
    u32 p1 = (u32)f2bf(a.z * invn) | ((u32)f2bf(a.w * invn) << 16);
    u32 p2 = (u32)f2bf(b.x * invn) | ((u32)f2bf(b.y * invn) << 16);
    u32 p3 = (u32)f2bf(b.z * invn) | ((u32)f2bf(b.w * invn) << 16);
    uint2 w0; w0.x = p0; w0.y = p1;
    uint2 w1; w1.x = p2; w1.y = p3;
    *(uint2*)&dst[l16 * 4] = w0;
    *(uint2*)&dst[64 + l16 * 4] = w1;
    if (l16 == 0) {
      if (is_q) qinv[row] = invn;
      else minv[mr] = pad ? 0.f : invn;
    }
  }
}

// ---------------- kernel 2 helpers ----------------
// 512 threads: each thread stages 2 x 16B units; 1024 units per 64x128 tile (XOR-swizzled)
static __device__ __forceinline__ void stage2(const u16* __restrict__ mn, u16* dst,
                                              int t, const u32* goff, u32 loff0) {
  const u16* gbase = mn + (size_t)t * MTILE * DDIM;
  #pragma unroll
  for (int it = 0; it < 2; ++it)
    async_copy16(gbase + goff[it], dst + loff0 + (u32)(it * 64) * 8);
}

// one 64-row tile with 32x32x16 MFMA (13% faster pipe than 16x16x32, half the insts):
// 16 MFMA + batch-max screening epilogue (packed code in mantissa).
// Screening stays IMMEDIATELY after the MFMAs: round-8 lesson — deferring it across the
// barrier extends acc's live range around the loop back-edge and the allocator SPILLS
// acc to scratch every round (FETCH 16.6MB -> 1.55GB, kgemm 92 -> 600 us). Keep acc local.
// Round-10 lesson: 3 blocks/CU (48KB ring-3, vmcnt(2)) REGRESSED (95.7 -> 101.7, MfmaUtil
// 53 -> 47): LDS-BW contention / residency cap. Keep 4-buffer, 2 blocks/CU, vmcnt(4).
static __device__ __forceinline__ void tileWork(
    const u16* As, int tl, int wm, int h, int l15, int l31,
    const bf16x8 (&bq)[2][8], float (&tv0)[2], float (&tv1)[2], float (&tv2)[2]) {
  f32x16 acc[2];  // [ni] : ni*32-wide query group
  __builtin_amdgcn_s_setprio(1);
  {
    int c = h ^ l15;  // s = 0
    bf16x8 a = *(const bf16x8*)&As[((wm * 32 + l31) * 16 + c) * 8];
    f32x16 z = {0.f,0.f,0.f,0.f,0.f,0.f,0.f,0.f,0.f,0.f,0.f,0.f,0.f,0.f,0.f,0.f};
    acc[0] = __builtin_amdgcn_mfma_f32_32x32x16_bf16(a, bq[0][0], z, 0, 0, 0);
    acc[1] = __builtin_amdgcn_mfma_f32_32x32x16_bf16(a, bq[1][0], z, 0, 0, 0);
  }
  #pragma unroll
  for (int s = 1; s < 8; ++s) {
    int c = (s * 2 + h) ^ l15;
    bf16x8 a = *(const bf16x8*)&As[((wm * 32 + l31) * 16 + c) * 8];
    acc[0] = __builtin_amdgcn_mfma_f32_32x32x16_bf16(a, bq[0][s], acc[0], 0, 0, 0);
    acc[1] = __builtin_amdgcn_mfma_f32_32x32x16_bf16(a, bq[1][s], acc[1], 0, 0, 0);
  }
  __builtin_amdgcn_s_setprio(0);
  const u32 codeBase = ((u32)tl << 2) | ((u32)h << 1);  // + g -> 9 bits < 512
  #pragma unroll
  for (int ni = 0; ni < 2; ++ni) {
    #pragma unroll
    for (int g = 0; g < 2; ++g) {
      float M = fmaxf(
          fmaxf(fmaxf(acc[ni][g * 8 + 0], acc[ni][g * 8 + 1]),
                fmaxf(acc[ni][g * 8 + 2], acc[ni][g * 8 + 3])),
          fmaxf(fmaxf(acc[ni][g * 8 + 4], acc[ni][g * 8 + 5]),
                fmaxf(acc[ni][g * 8 + 6], acc[ni][g * 8 + 7])));
      float pk = __uint_as_float((__float_as_uint(M) & 0xFFFFFE00u) | (codeBase | (u32)g));
      tv2[ni] = __builtin_amdgcn_fmed3f(tv1[ni], tv2[ni], pk);
      tv1[ni] = __builtin_amdgcn_fmed3f(tv0[ni], tv1[ni], pk);
      tv0[ni] = fmaxf(tv0[ni], pk);
    }
  }
}

// ---------------- kernel 2: 512-thread blocks (QTILE=256), 4-deep LDS pipeline ----------------
// grid 512 = 16 qtiles x 32 chunks (2 blocks/CU, 16 waves/CU). Stage tile t+3 while computing t;
// per round: s_waitcnt vmcnt(4) retires exactly the 3-round-old stage, then bare s_barrier.
// No vmcnt(0) drain in the main loop. (Round-2 lesson: coarsening with a drain REGRESSED.)
__global__ __launch_bounds__(512, 4) void kgemm(const u16* __restrict__ qn,
                                                const u16* __restrict__ mn,
                                                float* __restrict__ pval) {
  __shared__ u16 B0[MTILE * DDIM];  // 16 KB each, 64 KB total
  __shared__ u16 B1[MTILE * DDIM];
  __shared__ u16 B2[MTILE * DDIM];
  __shared__ u16 B3[MTILE * DDIM];

  const int id = blockIdx.x;                  // 0..511
  const int xcd = id & 7, sub = id >> 3;      // XCD-aware: 4 chunks per XCD (~3.1 MB in L2)
  const int ch = xcd * 4 + (sub >> 4);        // 0..31
  const int qt = sub & 15;                    // 0..15
  const int tid = threadIdx.x;
  const int wid = tid >> 6, lane = tid & 63;
  const int l15 = lane & 15, l31 = lane & 31, h = lane >> 5;
  const int wm = wid >> 2, wq = wid & 3;

  const int t0 = ch * TPC;
  const int t1 = (t0 + TPC < TOTAL_MT) ? (t0 + TPC) : TOTAL_MT;
  const int nt = t1 - t0;                     // 45..49

  // staging offsets: 2 x 16B units per thread; 1024 units per 64x128 tile (XOR-swizzled)
  u32 goff[2];
  u32 loff0;
  {
    int u0 = wid * 128 + lane;
    loff0 = (u32)(wid * 128) * 8;  // wave-uniform LDS base (HW adds lane*16B)
    #pragma unroll
    for (int it = 0; it < 2; ++it) {
      int u = u0 + it * 64;
      int row = u >> 4, su = u & 15;
      int k8 = su ^ (row & 15);
      goff[it] = (u32)(row * DDIM + k8 * 8);
    }
  }

  // prologue: stage tiles t0, t0+1, t0+2 (nt >= 45 always)
  stage2(mn, B0, t0 + 0, goff, loff0);
  stage2(mn, B1, t0 + 1, goff, loff0);
  stage2(mn, B2, t0 + 2, goff, loff0);

  // B (query) fragments for 32x32x16: col = l31-based, k = s*16 + h*8 .. +7 (64 VGPRs)
  bf16x8 bq[2][8];  // [ni][s]
  #pragma unroll
  for (int ni = 0; ni < 2; ++ni) {
    int col = qt * QTILE + wq * 64 + ni * 32 + l31;
    #pragma unroll
    for (int s = 0; s < 8; ++s)
      bq[ni][s] = *(const bf16x8*)&qn[(size_t)col * DDIM + (s * 2 + h) * 8];
  }

  float tv0[2], tv1[2], tv2[2];
  #pragma unroll
  for (int i = 0; i < 2; ++i) { tv0[i] = tv1[i] = tv2[i] = -1e30f; }

  asm volatile("s_waitcnt vmcnt(0)" ::: "memory");  // drain prologue stages (+bq loads)
  asm volatile("s_barrier" ::: "memory");

  // round r: stage min(t0+r+3, t1-1) into B[(r+3)&3]; compute B[r&3];
  // wait vmcnt(4) (retires stage r+1); bare barrier. Always 2 stage-insts/round
  // so the outstanding-count invariant holds in the tail.
  int r = 0;
  #define ROUND(BC, BS)                                                        \
    {                                                                          \
      int ts = t0 + r + 3;                                                     \
      ts = (ts < t1) ? ts : (t1 - 1);                                          \
      stage2(mn, BS, ts, goff, loff0);                                         \
      tileWork(BC, r, wm, h, l15, l31, bq, tv0, tv1, tv2);                     \
      asm volatile("s_waitcnt vmcnt(4)" ::: "memory");                         \
      asm volatile("s_barrier" ::: "memory");                                  \
      ++r;                                                                     \
      if (r >= nt) break;                                                      \
    }
  while (true) {
    ROUND(B0, B3)
    ROUND(B1, B0)
    ROUND(B2, B1)
    ROUND(B3, B2)
  }
  #undef ROUND

  // cross-h merge of sorted-3 lists (one shuffle level), then write 3 survivors per (col, wm)
  #pragma unroll
  for (int ni = 0; ni < 2; ++ni) {
    float a0 = tv0[ni], a1 = tv1[ni], a2 = tv2[ni];
    float b0 = __shfl_xor(a0, 32, 64);
    float b1 = __shfl_xor(a1, 32, 64);
    float b2 = __shfl_xor(a2, 32, 64);
    float n0 = fmaxf(a0, b0);
    float n1 = __builtin_amdgcn_fmed3f(a0, b0, fmaxf(a1, b1));
    float n2 = fmaxf(fmaxf(fminf(a1, b0), fminf(a0, b1)), fmaxf(a2, b2));
    int qlocal = wq * 64 + ni * 32 + l31;
    size_t base = (((size_t)qt * NCHUNK + ch) * QTILE + qlocal) * 6 + wm * 3;
    if (h == 0) {
      pval[base] = n0;
      pval[base + 1] = n1;
    } else {
      pval[base + 2] = n2;
    }
  }
}

// ---------------- kernel 3: radix-select top-8 batches, coalesced fp32 rescore, top-3 ----------------
__global__ __launch_bounds__(256) void kmerge(const float* __restrict__ pval,
                                              const float* __restrict__ q,
                                              const float* __restrict__ mem,
                                              const float* __restrict__ qinv,
                                              const float* __restrict__ minv,
                                              float* __restrict__ out) {
  __shared__ float sv[4][64];
  __shared__ u32 spk[4][8];   // packed float bits of the 8 winners
  __shared__ u32 spo[4][8];   // candidate positions of the 8 winners
  const int tid = threadIdx.x;
  const int wq = tid >> 6;
  const int lane = tid & 63;
  const int qg = blockIdx.x * 4 + wq;
  const int qt = qg >> 8, ql = qg & 255;

  // load 192 candidates: every lane owns 3 consecutive (within one 6-group half)
  const int c0 = lane * 3;
  float cv[3];
  {
    int chn = c0 / 6, rem = c0 - chn * 6;   // rem in {0,3}
    size_t b = (((size_t)qt * NCHUNK + chn) * QTILE + ql) * 6 + rem;
    cv[0] = pval[b];
    cv[1] = pval[b + 1];
    cv[2] = pval[b + 2];
  }

  // order-preserving uint keys (handles negatives)
  u32 k[3];
  #pragma unroll
  for (int i = 0; i < 3; ++i) {
    u32 u = __float_as_uint(cv[i]);
    k[i] = (u & 0x80000000u) ? ~u : (u | 0x80000000u);
  }

  // radix-select the 8th-largest key: 32 uniform rounds of {3 cmp, 2 ballot, 2 popc}.
  u32 t = 0;
  #pragma unroll
  for (int b = 31; b >= 0; --b) {
    u32 cand = t | (1u << b);
    int loc = (int)(k[0] >= cand) + (int)(k[1] >= cand) + (int)(k[2] >= cand);
    u64 B0 = __ballot(loc & 1);
    u64 B1 = __ballot(loc & 2);
    int cnt = __popcll(B0) + 2 * __popcll(B1);
    if (cnt >= 8) t = cand;
  }
  // t = 8th largest key: >=8 keys >= t, <=7 keys > t.

  // slot assignment: strictly-greater first (pos asc), then ==t fills remaining (pos asc).
  {
    u64 G[3], E[3];
    #pragma unroll
    for (int i = 0; i < 3; ++i) {
      G[i] = __ballot(k[i] > t);
      E[i] = __ballot(k[i] == t);
    }
    int c1 = __popcll(G[0]) + __popcll(G[1]) + __popcll(G[2]);
    int bg = mbcnt64(G[0]) + mbcnt64(G[1]) + mbcnt64(G[2]);  // strict winners in earlier lanes
    int be = mbcnt64(E[0]) + mbcnt64(E[1]) + mbcnt64(E[2]);  // ties in earlier lanes
    int og = 0, oe = 0;
    #pragma unroll
    for (int i = 0; i < 3; ++i) {
      int slot = 99;
      if (k[i] > t) { slot = bg + og; ++og; }
      else if (k[i] == t) { slot = c1 + be + oe; ++oe; }
      if (slot < 8) {
        spk[wq][slot] = __float_as_uint(cv[i]);
        spo[wq][slot] = (u32)(c0 + i);
      }
    }
  }
  __syncthreads();

  const float qi = qinv[qg];
  const float* qrow = q + (size_t)qg * DDIM;
  const int e = lane >> 3, f = lane & 7;

  // hoist the query row into registers: reused across all 8 batches
  float4 qv[4];
  #pragma unroll
  for (int i = 0; i < 4; ++i) qv[i] = *(const float4*)&qrow[(f + 8 * i) * 4];

  // rescore top-8 batches, 8 rows each; 8 lanes/row, 128B-coalesced segments.
  // batch decode (32x32x16 layout): code = tl<<2 | h<<1 | g;
  // row = tilebase + wm*32 + g*16 + (e>>2)*8 + h*4 + (e&3)
  #pragma unroll
  for (int p = 0; p < 8; ++p) {
    int bp = (int)spo[wq][p];
    u32 code = spk[wq][p] & 511u;
    int chn = bp / 6;
    int wm = (bp - chn * 6) / 3;
    int tl = (int)(code >> 2), hh = (int)((code >> 1) & 1u), g = (int)(code & 1u);
    int row = (chn * TPC + tl) * MTILE + wm * 32 + g * 16 + (e >> 2) * 8 + hh * 4 + (e & 3);
    bool valid = (row < N_M);
    int ra = valid ? row : 0;
    const float* mrow = mem + (size_t)ra * DDIM;
    float s = 0.f;
    #pragma unroll
    for (int i = 0; i < 4; ++i) {
      float4 mv = *(const float4*)&mrow[(f + 8 * i) * 4];
      s += qv[i].x * mv.x + qv[i].y * mv.y + qv[i].z * mv.z + qv[i].w * mv.w;
    }
    #pragma unroll
    for (int off = 1; off < 8; off <<= 1) s += __shfl_xor(s, off, 64);  // within octet
    s = valid ? (s * qi * minv[ra]) : -1e30f;
    if (f == 0) sv[wq][p * 8 + e] = s;
  }
  __syncthreads();

  // my (row, val): entry = lane -> pass p = lane>>3, elem e2 = lane&7
  float myv = sv[wq][lane];
  {
    int p = lane >> 3, e2 = lane & 7;
    int bp = (int)spo[wq][p];
    u32 code = spk[wq][p] & 511u;
    int chn = bp / 6;
    int wm = (bp - chn * 6) / 3;
    int tl = (int)(code >> 2), hh = (int)((code >> 1) & 1u), g = (int)(code & 1u);
    int row = (chn * TPC + tl) * MTILE + wm * 32 + g * 16 + (e2 >> 2) * 8 + hh * 4 + (e2 & 3);
    int myrow = (row < N_M) ? row : (N_M + lane);

    // 3 selection passes over 64 exact values (val desc, row asc)
    #pragma unroll
    for (int a = 0; a < 3; ++a) {
      float bv = myv; int bi = myrow;
      #pragma unroll
      for (int off = 32; off >= 1; off >>= 1) {
        float ov = __shfl_xor(bv, off, 64);
        int oi = __shfl_xor(bi, off, 64);
        bool g2 = (ov > bv) || (ov == bv && oi < bi);
        bv = g2 ? ov : bv; bi = g2 ? oi : bi;
      }
      if (lane == 0) {
        out[(size_t)qg * 3 + a] = 1.0f - bv;
        out[(size_t)N_Q * 3 + (size_t)qg * 3 + a] = (float)bi;
      }
      if (myrow == bi) myv = -1e31f;
    }
  }
}

extern "C" void kernel_launch(void* const* d_in, const int* in_sizes, int n_in,
                              void* d_out, int out_size, void* d_ws, size_t ws_size,
                              hipStream_t stream) {
  const float* q = (const float*)d_in[0];
  const float* m = (const float*)d_in[1];

  char* ws = (char*)d_ws;
  size_t off = 0;
  u16* qn = (u16*)(ws + off); off += (size_t)N_Q * DDIM * 2;        // 1 MB
  u16* mn = (u16*)(ws + off); off += (size_t)N_M_PAD * DDIM * 2;    // 25.6 MB
  float* qinv = (float*)(ws + off); off += (size_t)N_Q * 4;
  float* minv = (float*)(ws + off); off += (size_t)N_M_PAD * 4;
  float* pval = (float*)(ws + off); off += (size_t)N_Q * NCAND * 4; // 3 MB

  knorm<<<1024, 256, 0, stream>>>(q, m, qn, mn, qinv, minv);
  kgemm<<<NQT * NCHUNK, 512, 0, stream>>>(qn, mn, pval);
  kmerge<<<N_Q / 4, 256, 0, stream>>>(pval, q, m, qinv, minv, (float*)d_out);
}